// Round 4
// baseline (7286.298 us; speedup 1.0000x reference)
//
#include <hip/hip_runtime.h>
#include <hip/hip_bf16.h>

typedef unsigned short u16;
typedef __attribute__((ext_vector_type(8))) short bf16x8;
typedef __attribute__((ext_vector_type(4))) float f32x4;

#define T_ 128
#define B_ 32
#define I_ 128
#define H_ 128
#define R_ 100
#define O_ 64
#define NWG 100
#define SLICE (R_*B_*H_)      /* 409600 elems per H time slice */
#define XOFF  (T_*B_*I_)      /* x hi->lo offset */
#define WOFF  (R_*H_*H_)      /* weight hi->lo offset (I_==H_) */
#define OOFF  (O_*R_*H_)      /* Wout hi->lo offset */
#define CTN   (112*128)       /* CT hi->lo offset */

__device__ __forceinline__ float b2f(u16 u) {
  unsigned x = ((unsigned)u) << 16; float f; __builtin_memcpy(&f, &x, 4); return f;
}
__device__ __forceinline__ u16 f2b(float f) {
  unsigned x; __builtin_memcpy(&x, &f, 4);
  unsigned lsb = (x >> 16) & 1u;
  x += 0x7fffu + lsb;               // round-to-nearest-even
  return (u16)(x >> 16);
}
__device__ __forceinline__ void split2(float f, u16& hi, u16& lo) {
  hi = f2b(f);
  lo = f2b(f - b2f(hi));            // residual: pair carries ~16-17 mantissa bits
}
__device__ __forceinline__ float fast_tanh(float v) {
  float a = fabsf(v);
  float e = __expf(-2.f * a);
  float th = (1.f - e) * __builtin_amdgcn_rcpf(1.f + e);
  return v < 0.f ? -th : th;
}

// ---- dtype probe: mode=1 if d_in looks like fp32, 0 if bf16 ----
__global__ void __launch_bounds__(256)
probe_dtype(const u16* __restrict__ x, int* __restrict__ mode)
{
  __shared__ int cnt;
  if (threadIdx.x == 0) cnt = 0;
  __syncthreads();
  int bad = 0;
  for (int i = threadIdx.x; i < 8192; i += 256) {
    int ex = (x[i] >> 7) & 0xFF;
    if (ex >= 134) ++bad;           // |v|>=128: never in N(0,1) bf16
  }
  atomicAdd(&cnt, bad);
  __syncthreads();
  if (threadIdx.x == 0) *mode = (cnt > 256) ? 1 : 0;
}

__device__ __forceinline__ float load_in(const void* p, size_t i, int f32) {
  return f32 ? ((const float*)p)[i] : b2f(((const u16*)p)[i]);
}

// elementwise -> split bf16 pair
__global__ void __launch_bounds__(256)
conv_split(const void* __restrict__ src, u16* __restrict__ hi, u16* __restrict__ lo,
           const int* __restrict__ mode, int n)
{
  int i = blockIdx.x * 256 + threadIdx.x;
  if (i < n) { u16 h, l; split2(load_in(src, i, *mode), h, l); hi[i] = h; lo[i] = l; }
}

// elementwise -> fp32
__global__ void __launch_bounds__(256)
conv_vec(const void* __restrict__ src, float* __restrict__ dst,
         const int* __restrict__ mode, int n)
{
  int i = blockIdx.x * 256 + threadIdx.x;
  if (i < n) dst[i] = load_in(src, i, *mode);
}

// Tiled transpose: in[m][KK][NN] -> hi/lo[m][NN][KK]; grid = m*(KK/32)*(NN/32)
__global__ void __launch_bounds__(256)
transpose_kn2(const void* __restrict__ in, u16* __restrict__ ohi, u16* __restrict__ olo,
              int KK, int NN, const int* __restrict__ mode)
{
  __shared__ float tile[32][33];
  const int f32 = *mode;
  int ntk = KK >> 5, ntn = NN >> 5;
  int bid = blockIdx.x;
  int m  = bid / (ntk * ntn);
  int rem = bid % (ntk * ntn);
  int kt = rem / ntn, nt = rem % ntn;
  size_t base = (size_t)m * KK * NN;
  int tid = threadIdx.x;
  int tc = tid & 31, tr0 = tid >> 5;
  #pragma unroll
  for (int rr = 0; rr < 4; ++rr) {
    int tr = tr0 + rr * 8;
    tile[tr][tc] = load_in(in, base + (size_t)(kt*32 + tr) * NN + nt*32 + tc, f32);
  }
  __syncthreads();
  #pragma unroll
  for (int rr = 0; rr < 4; ++rr) {
    int tr = tr0 + rr * 8;
    u16 h, l; split2(tile[tc][tr], h, l);
    size_t di = base + (size_t)(nt*32 + tr) * KK + kt*32 + tc;
    ohi[di] = h; olo[di] = l;
  }
}

// CT_pad[j][i] = C[i][j], padded to 112x128, split
__global__ void __launch_bounds__(256)
make_ct2(const void* __restrict__ C, u16* __restrict__ CT, const int* __restrict__ mode)
{
  int idx = blockIdx.x * 256 + threadIdx.x;   // 112*128
  if (idx < CTN) {
    int j = idx >> 7, i = idx & 127;
    float v = (j < R_ && i < R_) ? load_in(C, (size_t)i * R_ + j, *mode) : 0.f;
    u16 h, l; split2(v, h, l);
    CT[idx] = h; CT[CTN + idx] = l;
  }
}

// Distributed flag barrier; spin cap guarantees termination.
__device__ __forceinline__ void grid_barrier(int* flags, int gen, int w, int tid) {
  __syncthreads();
  if (tid == 0) {
    __threadfence();               // agent release
    __hip_atomic_store(&flags[w * 32], gen, __ATOMIC_RELEASE, __HIP_MEMORY_SCOPE_AGENT);
  }
  if (tid < NWG) {
    int spins = 0;
    while (__hip_atomic_load(&flags[tid * 32], __ATOMIC_RELAXED, __HIP_MEMORY_SCOPE_AGENT) < gen) {
      __builtin_amdgcn_s_sleep(2);
      if (++spins > (1 << 17)) break;
    }
  }
  __syncthreads();
  __threadfence();                 // agent acquire
}

#define MFMA3(ACC, AH, AL, BH, BL) \
  ACC = __builtin_amdgcn_mfma_f32_16x16x32_bf16(AL, BH, ACC); \
  ACC = __builtin_amdgcn_mfma_f32_16x16x32_bf16(AH, BL, ACC); \
  ACC = __builtin_amdgcn_mfma_f32_16x16x32_bf16(AH, BH, ACC);

__device__ __forceinline__ f32x4 mfma_(bf16x8 a, bf16x8 b, f32x4 c) {
  return __builtin_amdgcn_mfma_f32_16x16x32_bf16(a, b, c, 0, 0, 0);
}

__global__ void __launch_bounds__(256)
rnn_kernel(const u16* __restrict__ x,   // hi | lo(+XOFF)
           u16* __restrict__ Hb,        // slice s: hi at 2s*SLICE, lo at (2s+1)*SLICE
           u16* __restrict__ msg,       // hi | lo(+SLICE)
           const u16* __restrict__ WihT, const u16* __restrict__ WhhT,
           const u16* __restrict__ WrhhT,                 // hi | lo(+WOFF)
           const u16* __restrict__ CT,                    // hi | lo(+CTN)
           const float* __restrict__ biasf,
           const u16* __restrict__ WoutT,                 // hi | lo(+OOFF)
           float* __restrict__ part, const float* __restrict__ boutf,
           float* __restrict__ out, int* __restrict__ flags)
{
  const int w    = blockIdx.x;       // 0..99 ; phase B region = w
  const int tid  = threadIdx.x;
  const int lane = tid & 63;
  const int wv   = tid >> 6;
  const int l15  = lane & 15;
  const int quad = lane >> 4;

  __shared__ u16 HThi[64 * 136];     // phase A: HT[col][i]; epilogue: Ht[b][h]
  __shared__ u16 HTlo[64 * 136];

  int gen = 0;
  const int r = w;

  for (int t = 0; t < T_; ++t) {
    const u16* Hprev = Hb + (size_t)2 * (t & 1) * SLICE;        // hi; lo at +SLICE
    u16*       Hnext = Hb + (size_t)2 * ((t + 1) & 1) * SLICE;

    // -------- phase A: msg = C^T @ Hprev (WGs 0..63 own 64 columns each) --------
    if (w < 64) {
      const int b  = w >> 1;
      const int h0 = (w & 1) * 64;
      #pragma unroll
      for (int it = 0; it < 8; ++it) {
        int idx = tid + it * 256;          // 128 i x 16 col-quads
        int i = idx >> 4, c4 = idx & 15;
        ushort4 vh = {0,0,0,0}, vl = {0,0,0,0};
        if (i < R_) {
          const u16* p = Hprev + (size_t)i * (B_*H_) + b * H_ + h0 + c4 * 4;
          vh = *(const ushort4*)p;
          vl = *(const ushort4*)(p + SLICE);
        }
        int c = c4 * 4;
        HThi[(c+0)*136 + i] = vh.x; HThi[(c+1)*136 + i] = vh.y;
        HThi[(c+2)*136 + i] = vh.z; HThi[(c+3)*136 + i] = vh.w;
        HTlo[(c+0)*136 + i] = vl.x; HTlo[(c+1)*136 + i] = vl.y;
        HTlo[(c+2)*136 + i] = vl.z; HTlo[(c+3)*136 + i] = vl.w;
      }
      __syncthreads();
      const int colL = wv * 16 + l15;
      const int colG = b * H_ + h0 + colL;
      #pragma unroll
      for (int mt = 0; mt < 7; ++mt) {           // j tiles (112 = 7*16)
        f32x4 acc = {0.f, 0.f, 0.f, 0.f};
        #pragma unroll
        for (int k = 0; k < 4; ++k) {            // K = 128 (i, zero-padded)
          int i0 = k * 32 + quad * 8;
          const u16* ap = CT + (size_t)(mt*16 + l15) * 128 + i0;
          bf16x8 ah = *(const bf16x8*)ap;
          bf16x8 al = *(const bf16x8*)(ap + CTN);
          bf16x8 bh = *(const bf16x8*)(&HThi[colL * 136 + i0]);
          bf16x8 bl = *(const bf16x8*)(&HTlo[colL * 136 + i0]);
          acc = mfma_(al, bh, acc); acc = mfma_(ah, bl, acc); acc = mfma_(ah, bh, acc);
        }
        #pragma unroll
        for (int rr = 0; rr < 4; ++rr) {
          int j = mt * 16 + quad * 4 + rr;
          if (j < R_) {
            u16 h, l; split2(acc[rr], h, l);
            size_t mi = (size_t)j * (B_*H_) + colG;
            msg[mi] = h; msg[SLICE + mi] = l;
          }
        }
      }
    } else if (w < 72 && t > 0) {
      // -------- reducers: out[t-1][b][o] = sum_r part[r][b][o] + b_out[o] --------
      int e = (w - 64) * 256 + tid;              // 0..2047 = b*64+o
      float s = 0.f;
      #pragma unroll 4
      for (int r2 = 0; r2 < R_; ++r2) s += part[r2 * (B_*O_) + e];
      out[(size_t)(t-1) * (B_*O_) + e] = s + boutf[e & (O_-1)];
    }
    ++gen; grid_barrier(flags, gen, w, tid);

    // -------- phase B: Ht[r] = tanh([x_t|Hprev[r]|msg[r]] @ Wcat[r] + bias) --------
    f32x4 acc00 = {0,0,0,0}, acc01 = {0,0,0,0}, acc10 = {0,0,0,0}, acc11 = {0,0,0,0};
    const int n0 = wv, n1 = wv + 4;
    #pragma unroll
    for (int seg = 0; seg < 3; ++seg) {
      const u16* Ah; const u16* Bh; size_t alo;
      if (seg == 0)      { Ah = x     + (size_t)t * (B_*I_); Bh = WihT  + (size_t)r * (H_*I_); alo = XOFF; }
      else if (seg == 1) { Ah = Hprev + (size_t)r * (B_*H_); Bh = WhhT  + (size_t)r * (H_*H_); alo = SLICE; }
      else               { Ah = msg   + (size_t)r * (B_*H_); Bh = WrhhT + (size_t)r * (H_*H_); alo = SLICE; }
      #pragma unroll
      for (int kk = 0; kk < 4; ++kk) {
        int koff = kk * 32 + quad * 8;
        const u16* pa0 = Ah + (size_t)l15 * 128 + koff;
        const u16* pa1 = Ah + (size_t)(16 + l15) * 128 + koff;
        const u16* pb0 = Bh + (size_t)(n0*16 + l15) * 128 + koff;
        const u16* pb1 = Bh + (size_t)(n1*16 + l15) * 128 + koff;
        bf16x8 a0h = *(const bf16x8*)pa0, a0l = *(const bf16x8*)(pa0 + alo);
        bf16x8 a1h = *(const bf16x8*)pa1, a1l = *(const bf16x8*)(pa1 + alo);
        bf16x8 b0h = *(const bf16x8*)pb0, b0l = *(const bf16x8*)(pb0 + WOFF);
        bf16x8 b1h = *(const bf16x8*)pb1, b1l = *(const bf16x8*)(pb1 + WOFF);
        acc00 = mfma_(a0l,b0h, mfma_(a0h,b0l, mfma_(a0h,b0h, acc00)));
        acc10 = mfma_(a1l,b0h, mfma_(a1h,b0l, mfma_(a1h,b0h, acc10)));
        acc01 = mfma_(a0l,b1h, mfma_(a0h,b1l, mfma_(a0h,b1h, acc01)));
        acc11 = mfma_(a1l,b1h, mfma_(a1h,b1l, mfma_(a1h,b1h, acc11)));
      }
    }
    // epilogue: tanh (fp32) -> split bf16; store to Hnext (global) and LDS
    {
      u16* Hn = Hnext + (size_t)r * (B_*H_);     // hi; lo at +SLICE
      float bs0 = biasf[r*H_ + n0*16 + l15];
      float bs1 = biasf[r*H_ + n1*16 + l15];
      #pragma unroll
      for (int rr = 0; rr < 4; ++rr) {
        int b0r = quad*4 + rr;
        int b1r = 16 + quad*4 + rr;
        u16 h, l;
        split2(fast_tanh(acc00[rr] + bs0), h, l);
        Hn[b0r*H_ + n0*16 + l15] = h; Hn[SLICE + b0r*H_ + n0*16 + l15] = l;
        HThi[b0r*136 + n0*16 + l15] = h; HTlo[b0r*136 + n0*16 + l15] = l;
        split2(fast_tanh(acc10[rr] + bs0), h, l);
        Hn[b1r*H_ + n0*16 + l15] = h; Hn[SLICE + b1r*H_ + n0*16 + l15] = l;
        HThi[b1r*136 + n0*16 + l15] = h; HTlo[b1r*136 + n0*16 + l15] = l;
        split2(fast_tanh(acc01[rr] + bs1), h, l);
        Hn[b0r*H_ + n1*16 + l15] = h; Hn[SLICE + b0r*H_ + n1*16 + l15] = l;
        HThi[b0r*136 + n1*16 + l15] = h; HTlo[b0r*136 + n1*16 + l15] = l;
        split2(fast_tanh(acc11[rr] + bs1), h, l);
        Hn[b1r*H_ + n1*16 + l15] = h; Hn[SLICE + b1r*H_ + n1*16 + l15] = l;
        HThi[b1r*136 + n1*16 + l15] = h; HTlo[b1r*136 + n1*16 + l15] = l;
      }
    }
    __syncthreads();   // LDS Ht tile ready

    // -------- fused out-projection: part[r] = Ht[r] @ Wout[r] (fp32) --------
    {
      const int o = wv * 16 + l15;
      const u16* Bo = WoutT + (size_t)o * (R_*H_) + (size_t)r * H_;
      f32x4 y0 = {0,0,0,0}, y1 = {0,0,0,0};
      #pragma unroll
      for (int kk = 0; kk < 4; ++kk) {
        int koff = kk * 32 + quad * 8;
        bf16x8 a0h = *(const bf16x8*)(&HThi[l15 * 136 + koff]);
        bf16x8 a0l = *(const bf16x8*)(&HTlo[l15 * 136 + koff]);
        bf16x8 a1h = *(const bf16x8*)(&HThi[(16 + l15) * 136 + koff]);
        bf16x8 a1l = *(const bf16x8*)(&HTlo[(16 + l15) * 136 + koff]);
        bf16x8 b0h = *(const bf16x8*)(Bo + koff);
        bf16x8 b0l = *(const bf16x8*)(Bo + OOFF + koff);
        y0 = mfma_(a0l,b0h, mfma_(a0h,b0l, mfma_(a0h,b0h, y0)));
        y1 = mfma_(a1l,b0h, mfma_(a1h,b0l, mfma_(a1h,b0h, y1)));
      }
      float* pp = part + (size_t)r * (B_*O_);
      #pragma unroll
      for (int rr = 0; rr < 4; ++rr) {
        pp[(quad*4 + rr)*O_ + o]      = y0[rr];
        pp[(16 + quad*4 + rr)*O_ + o] = y1[rr];
      }
    }
    ++gen; grid_barrier(flags, gen, w, tid);
  }

  // -------- tail: reduce partials of step T-1 --------
  if (w >= 64 && w < 72) {
    int e = (w - 64) * 256 + tid;
    float s = 0.f;
    #pragma unroll 4
    for (int r2 = 0; r2 < R_; ++r2) s += part[r2 * (B_*O_) + e];
    out[(size_t)(T_-1) * (B_*O_) + e] = s + boutf[e & (O_-1)];
  }
}

extern "C" void kernel_launch(void* const* d_in, const int* in_sizes, int n_in,
                              void* d_out, int out_size, void* d_ws, size_t ws_size,
                              hipStream_t stream) {
  const void* xp    = d_in[0];
  const void* Cp    = d_in[1];
  const void* Wih   = d_in[2];
  const void* Whh   = d_in[3];
  const void* Wrhh  = d_in[4];
  const void* biasp = d_in[5];
  const void* Wout  = d_in[6];
  const void* boutp = d_in[7];
  float* outp = (float*)d_out;    // fp32 output (inputs proven fp32; ref returns fp32)

  char* ws = (char*)d_ws;
  size_t off = 0;
  auto carve = [&](size_t bytes) -> void* {
    void* p = ws + off;
    off += (bytes + 255) & ~(size_t)255;
    return p;
  };
  u16*   xb    = (u16*)carve((size_t)2 * XOFF * 2);            // hi|lo, 2 MB
  u16*   Hb    = (u16*)carve((size_t)4 * SLICE * 2);           // 2 slices x hi|lo, 3.3 MB
  u16*   msgp  = (u16*)carve((size_t)2 * SLICE * 2);           // hi|lo, 1.6 MB
  u16*   wihT  = (u16*)carve((size_t)2 * WOFF * 2);            // 6.6 MB
  u16*   whhT  = (u16*)carve((size_t)2 * WOFF * 2);
  u16*   wrhhT = (u16*)carve((size_t)2 * WOFF * 2);
  u16*   woutT = (u16*)carve((size_t)2 * OOFF * 2);            // 3.3 MB
  u16*   ctp   = (u16*)carve((size_t)2 * CTN * 2);
  float* biasf = (float*)carve((size_t)R_ * H_ * 4);
  float* boutf = (float*)carve((size_t)O_ * 4);
  float* partp = (float*)carve((size_t)R_ * B_ * O_ * 4);      // 0.8 MB
  int*   flagp = (int*)carve((size_t)NWG * 32 * 4);
  int*   modep = (int*)carve(256);
  // total ~32 MB

  // ws is re-poisoned before every launch: zero what must start at zero
  hipMemsetAsync(Hb, 0, (size_t)2 * SLICE * 2, stream);        // H_0 hi+lo = 0
  hipMemsetAsync(flagp, 0, (size_t)NWG * 32 * 4, stream);

  // dtype probe + conversions (dtype-agnostic via mode flag)
  probe_dtype<<<dim3(1), dim3(256), 0, stream>>>((const u16*)xp, modep);
  conv_split<<<dim3((XOFF + 255)/256), dim3(256), 0, stream>>>(xp, xb, xb + XOFF, modep, XOFF);
  conv_vec<<<dim3((R_*H_ + 255)/256), dim3(256), 0, stream>>>(biasp, biasf, modep, R_*H_);
  conv_vec<<<dim3(1), dim3(256), 0, stream>>>(boutp, boutf, modep, O_);

  // weight transposes -> split hi/lo, K-contiguous for MFMA fragments
  transpose_kn2<<<dim3(R_ * 16), dim3(256), 0, stream>>>(Wih,  wihT,  wihT  + WOFF, I_, H_, modep);
  transpose_kn2<<<dim3(R_ * 16), dim3(256), 0, stream>>>(Whh,  whhT,  whhT  + WOFF, H_, H_, modep);
  transpose_kn2<<<dim3(R_ * 16), dim3(256), 0, stream>>>(Wrhh, wrhhT, wrhhT + WOFF, H_, H_, modep);
  transpose_kn2<<<dim3(800),     dim3(256), 0, stream>>>(Wout, woutT, woutT + OOFF, R_ * H_, O_, modep);
  make_ct2<<<dim3(56), dim3(256), 0, stream>>>(Cp, ctp, modep);

  // persistent recurrence: NORMAL launch (100 WGs co-resident on 256 CUs)
  rnn_kernel<<<dim3(NWG), dim3(256), 0, stream>>>(
      xb, Hb, msgp, wihT, whhT, wrhhT, ctp, biasf, woutT, partp, boutf, outp, flagp);
}

// Round 5
// 5101.231 us; speedup vs baseline: 1.4283x; 1.4283x over previous
//
#include <hip/hip_runtime.h>
#include <hip/hip_bf16.h>

typedef unsigned short u16;
typedef unsigned long long ull;
typedef __attribute__((ext_vector_type(8))) short bf16x8;
typedef __attribute__((ext_vector_type(4))) float f32x4;

#define T_ 128
#define B_ 32
#define I_ 128
#define H_ 128
#define R_ 100
#define O_ 64
#define NWG 100
#define SLICE (R_*B_*H_)      /* 409600 elems per H time slice */
#define XOFF  (T_*B_*I_)      /* x hi->lo offset */
#define WOFF  (R_*H_*H_)      /* weight hi->lo offset (I_==H_) */
#define OOFF  (O_*R_*H_)      /* Wout hi->lo offset */
#define CTN   (112*128)       /* CT hi->lo offset */

__device__ __forceinline__ float b2f(u16 u) {
  unsigned x = ((unsigned)u) << 16; float f; __builtin_memcpy(&f, &x, 4); return f;
}
__device__ __forceinline__ u16 f2b(float f) {
  unsigned x; __builtin_memcpy(&x, &f, 4);
  unsigned lsb = (x >> 16) & 1u;
  x += 0x7fffu + lsb;               // round-to-nearest-even
  return (u16)(x >> 16);
}
__device__ __forceinline__ void split2(float f, u16& hi, u16& lo) {
  hi = f2b(f);
  lo = f2b(f - b2f(hi));            // pair carries ~16-17 mantissa bits
}
__device__ __forceinline__ float fast_tanh(float v) {
  float a = fabsf(v);
  float e = __expf(-2.f * a);
  float th = (1.f - e) * __builtin_amdgcn_rcpf(1.f + e);
  return v < 0.f ? -th : th;
}

// ---- relaxed agent-scope (cross-XCD coherent, fence-free) accessors ----
__device__ __forceinline__ ull ald8(const void* p) {
  return __hip_atomic_load((ull*)p, __ATOMIC_RELAXED, __HIP_MEMORY_SCOPE_AGENT);
}
__device__ __forceinline__ void ast8(void* p, ull v) {
  __hip_atomic_store((ull*)p, v, __ATOMIC_RELAXED, __HIP_MEMORY_SCOPE_AGENT);
}
__device__ __forceinline__ float aldf(const float* p) {
  return __hip_atomic_load((float*)p, __ATOMIC_RELAXED, __HIP_MEMORY_SCOPE_AGENT);
}
__device__ __forceinline__ void astf(float* p, float v) {
  __hip_atomic_store(p, v, __ATOMIC_RELAXED, __HIP_MEMORY_SCOPE_AGENT);
}
__device__ __forceinline__ bf16x8 ald16(const u16* p) {   // 16B via 2x coherent 8B
  union { ull q[2]; bf16x8 v; } u;
  u.q[0] = ald8(p); u.q[1] = ald8(p + 4);
  return u.v;
}

// ---- dtype probe: mode=1 if d_in looks like fp32, 0 if bf16 ----
__global__ void __launch_bounds__(256)
probe_dtype(const u16* __restrict__ x, int* __restrict__ mode)
{
  __shared__ int cnt;
  if (threadIdx.x == 0) cnt = 0;
  __syncthreads();
  int bad = 0;
  for (int i = threadIdx.x; i < 8192; i += 256) {
    int ex = (x[i] >> 7) & 0xFF;
    if (ex >= 134) ++bad;           // |v|>=128: never in N(0,1) bf16
  }
  atomicAdd(&cnt, bad);
  __syncthreads();
  if (threadIdx.x == 0) *mode = (cnt > 256) ? 1 : 0;
}

__device__ __forceinline__ float load_in(const void* p, size_t i, int f32) {
  return f32 ? ((const float*)p)[i] : b2f(((const u16*)p)[i]);
}

__global__ void __launch_bounds__(256)
conv_split(const void* __restrict__ src, u16* __restrict__ hi, u16* __restrict__ lo,
           const int* __restrict__ mode, int n)
{
  int i = blockIdx.x * 256 + threadIdx.x;
  if (i < n) { u16 h, l; split2(load_in(src, i, *mode), h, l); hi[i] = h; lo[i] = l; }
}

__global__ void __launch_bounds__(256)
conv_vec(const void* __restrict__ src, float* __restrict__ dst,
         const int* __restrict__ mode, int n)
{
  int i = blockIdx.x * 256 + threadIdx.x;
  if (i < n) dst[i] = load_in(src, i, *mode);
}

// Tiled transpose: in[m][KK][NN] -> hi/lo[m][NN][KK]; grid = m*(KK/32)*(NN/32)
__global__ void __launch_bounds__(256)
transpose_kn2(const void* __restrict__ in, u16* __restrict__ ohi, u16* __restrict__ olo,
              int KK, int NN, const int* __restrict__ mode)
{
  __shared__ float tile[32][33];
  const int f32 = *mode;
  int ntk = KK >> 5, ntn = NN >> 5;
  int bid = blockIdx.x;
  int m  = bid / (ntk * ntn);
  int rem = bid % (ntk * ntn);
  int kt = rem / ntn, nt = rem % ntn;
  size_t base = (size_t)m * KK * NN;
  int tid = threadIdx.x;
  int tc = tid & 31, tr0 = tid >> 5;
  #pragma unroll
  for (int rr = 0; rr < 4; ++rr) {
    int tr = tr0 + rr * 8;
    tile[tr][tc] = load_in(in, base + (size_t)(kt*32 + tr) * NN + nt*32 + tc, f32);
  }
  __syncthreads();
  #pragma unroll
  for (int rr = 0; rr < 4; ++rr) {
    int tr = tr0 + rr * 8;
    u16 h, l; split2(tile[tc][tr], h, l);
    size_t di = base + (size_t)(nt*32 + tr) * KK + kt*32 + tc;
    ohi[di] = h; olo[di] = l;
  }
}

// CT_pad[j][i] = C[i][j], padded to 112x128, split
__global__ void __launch_bounds__(256)
make_ct2(const void* __restrict__ C, u16* __restrict__ CT, const int* __restrict__ mode)
{
  int idx = blockIdx.x * 256 + threadIdx.x;
  if (idx < CTN) {
    int j = idx >> 7, i = idx & 127;
    float v = (j < R_ && i < R_) ? load_in(C, (size_t)i * R_ + j, *mode) : 0.f;
    u16 h, l; split2(v, h, l);
    CT[idx] = h; CT[CTN + idx] = l;
  }
}

// Fence-free distributed barrier: all cross-WG data moved via sc1 (agent-scope)
// atomics, so no L2 writeback/invalidate is needed. __syncthreads drains each
// wave's vmcnt before s_barrier => all sc1 stores globally visible before the
// flag posts. Spin cap guarantees termination.
__device__ __forceinline__ void grid_barrier(int* flags, int gen, int w, int tid) {
  __syncthreads();
  if (tid == 0)
    __hip_atomic_store(&flags[w * 32], gen, __ATOMIC_RELAXED, __HIP_MEMORY_SCOPE_AGENT);
  if (tid < NWG) {
    int spins = 0;
    while (__hip_atomic_load(&flags[tid * 32], __ATOMIC_RELAXED, __HIP_MEMORY_SCOPE_AGENT) < gen) {
      __builtin_amdgcn_s_sleep(1);
      if (++spins > (1 << 16)) break;   // failsafe: wrong-but-terminating beats hang
    }
  }
  asm volatile("" ::: "memory");        // compiler-only: no hoisting loads above spin
  __syncthreads();
}

__device__ __forceinline__ f32x4 mfma_(bf16x8 a, bf16x8 b, f32x4 c) {
  return __builtin_amdgcn_mfma_f32_16x16x32_bf16(a, b, c, 0, 0, 0);
}

__global__ void __launch_bounds__(256)
rnn_kernel(const u16* __restrict__ x,   // hi | lo(+XOFF)   (read-only, cached)
           u16* __restrict__ Hb,        // slice s: hi at 2s*SLICE, lo at +SLICE (sc1)
           u16* __restrict__ msg,       // hi | lo(+SLICE)  (sc1)
           const u16* __restrict__ WihT, const u16* __restrict__ WhhT,
           const u16* __restrict__ WrhhT,                 // hi | lo(+WOFF), cached
           const u16* __restrict__ CT,                    // hi | lo(+CTN), cached
           const float* __restrict__ biasf,
           const u16* __restrict__ WoutT,                 // hi | lo(+OOFF), cached
           float* __restrict__ part, const float* __restrict__ boutf,
           float* __restrict__ out, int* __restrict__ flags)
{
  const int w    = blockIdx.x;       // 0..99 ; phase B region = w
  const int tid  = threadIdx.x;
  const int lane = tid & 63;
  const int wv   = tid >> 6;
  const int l15  = lane & 15;
  const int quad = lane >> 4;

  __shared__ u16 HThi[64 * 136];     // phase A staging: HT[col][i]
  __shared__ u16 HTlo[64 * 136];
  __shared__ u16 Hmhi[32 * 136];     // persistent own-region H_t (pitch 136)
  __shared__ u16 Hmlo[32 * 136];
  __shared__ u16 mShi[112 * 68];     // phase A msg staging (pitch 68)
  __shared__ u16 mSlo[112 * 68];

  // H_0 = 0 in LDS copy
  for (int e = tid; e < 32 * 136; e += 256) { Hmhi[e] = 0; Hmlo[e] = 0; }
  __syncthreads();

  int gen = 0;
  const int r = w;

  for (int t = 0; t < T_; ++t) {
    const u16* Hprev = Hb + (size_t)2 * (t & 1) * SLICE;        // hi; lo at +SLICE
    u16*       Hnext = Hb + (size_t)2 * ((t + 1) & 1) * SLICE;

    // -------- phase A: msg = C^T @ Hprev (WGs 0..63; 64 columns each) --------
    if (w < 64) {
      const int b  = w >> 1;
      const int h0 = (w & 1) * 64;
      #pragma unroll
      for (int it = 0; it < 8; ++it) {
        int idx = tid + it * 256;          // 128 i x 16 col-quads
        int i = idx >> 4, c4 = idx & 15;
        ull qh = 0, ql = 0;
        if (i < R_) {
          const u16* p = Hprev + (size_t)i * (B_*H_) + b * H_ + h0 + c4 * 4;
          qh = ald8(p);
          ql = ald8(p + SLICE);
        }
        union { ull q; u16 s[4]; } uh, ul;
        uh.q = qh; ul.q = ql;
        int c = c4 * 4;
        HThi[(c+0)*136 + i] = uh.s[0]; HThi[(c+1)*136 + i] = uh.s[1];
        HThi[(c+2)*136 + i] = uh.s[2]; HThi[(c+3)*136 + i] = uh.s[3];
        HTlo[(c+0)*136 + i] = ul.s[0]; HTlo[(c+1)*136 + i] = ul.s[1];
        HTlo[(c+2)*136 + i] = ul.s[2]; HTlo[(c+3)*136 + i] = ul.s[3];
      }
      __syncthreads();
      const int colL = wv * 16 + l15;
      #pragma unroll
      for (int mt = 0; mt < 7; ++mt) {           // j tiles (112 = 7*16)
        f32x4 acc = {0.f, 0.f, 0.f, 0.f};
        #pragma unroll
        for (int k = 0; k < 4; ++k) {            // K = 128 (i, zero-padded)
          int i0 = k * 32 + quad * 8;
          const u16* ap = CT + (size_t)(mt*16 + l15) * 128 + i0;
          bf16x8 ah = *(const bf16x8*)ap;
          bf16x8 al = *(const bf16x8*)(ap + CTN);
          bf16x8 bh = *(const bf16x8*)(&HThi[colL * 136 + i0]);
          bf16x8 bl = *(const bf16x8*)(&HTlo[colL * 136 + i0]);
          acc = mfma_(al, bh, acc); acc = mfma_(ah, bl, acc); acc = mfma_(ah, bh, acc);
        }
        #pragma unroll
        for (int rr = 0; rr < 4; ++rr) {
          int j = mt * 16 + quad * 4 + rr;
          u16 h, l; split2(acc[rr], h, l);
          mShi[j * 68 + colL] = h;
          mSlo[j * 68 + colL] = l;
        }
      }
      __syncthreads();
      // coalesced coherent msg write: rows j<100, 64-col stripe
      for (int e = tid; e < 100 * 16; e += 256) {
        int j = e >> 4, c = (e & 15) * 4;
        size_t gi = (size_t)j * (B_*H_) + b * H_ + h0 + c;
        ast8(msg + gi,         *(const ull*)&mShi[j * 68 + c]);
        ast8(msg + SLICE + gi, *(const ull*)&mSlo[j * 68 + c]);
      }
    } else if (w < 72 && t > 0) {
      // -------- reducers: out[t-1][b][o] = sum_r part[r][b][o] + b_out[o] --------
      int e = (w - 64) * 256 + tid;              // 0..2047 = b*64+o
      float s = 0.f;
      #pragma unroll 4
      for (int r2 = 0; r2 < R_; ++r2) s += aldf(part + r2 * (B_*O_) + e);
      out[(size_t)(t-1) * (B_*O_) + e] = s + boutf[e & (O_-1)];
    }
    ++gen; grid_barrier(flags, gen, w, tid);

    // -------- phase B: Ht[r] = tanh([x_t|H_t[r]|msg[r]] @ Wcat[r] + bias) --------
    f32x4 acc00 = {0,0,0,0}, acc01 = {0,0,0,0}, acc10 = {0,0,0,0}, acc11 = {0,0,0,0};
    const int n0 = wv, n1 = wv + 4;
    {
      // seg0: x (cached) ; seg1: own H from LDS ; seg2: msg (coherent)
      const u16* Ax  = x + (size_t)t * (B_*I_);
      const u16* Bw0 = WihT  + (size_t)r * (H_*I_);
      const u16* Bw1 = WhhT  + (size_t)r * (H_*H_);
      const u16* Bw2 = WrhhT + (size_t)r * (H_*H_);
      const u16* Am  = msg + (size_t)r * (B_*H_);
      #pragma unroll
      for (int kk = 0; kk < 4; ++kk) {
        int koff = kk * 32 + quad * 8;
        // --- seg0 ---
        {
          const u16* pa0 = Ax + (size_t)l15 * 128 + koff;
          const u16* pa1 = Ax + (size_t)(16 + l15) * 128 + koff;
          bf16x8 a0h = *(const bf16x8*)pa0, a0l = *(const bf16x8*)(pa0 + XOFF);
          bf16x8 a1h = *(const bf16x8*)pa1, a1l = *(const bf16x8*)(pa1 + XOFF);
          const u16* pb0 = Bw0 + (size_t)(n0*16 + l15) * 128 + koff;
          const u16* pb1 = Bw0 + (size_t)(n1*16 + l15) * 128 + koff;
          bf16x8 b0h = *(const bf16x8*)pb0, b0l = *(const bf16x8*)(pb0 + WOFF);
          bf16x8 b1h = *(const bf16x8*)pb1, b1l = *(const bf16x8*)(pb1 + WOFF);
          acc00 = mfma_(a0l,b0h, mfma_(a0h,b0l, mfma_(a0h,b0h, acc00)));
          acc10 = mfma_(a1l,b0h, mfma_(a1h,b0l, mfma_(a1h,b0h, acc10)));
          acc01 = mfma_(a0l,b1h, mfma_(a0h,b1l, mfma_(a0h,b1h, acc01)));
          acc11 = mfma_(a1l,b1h, mfma_(a1h,b1l, mfma_(a1h,b1h, acc11)));
        }
        // --- seg1 (LDS) ---
        {
          bf16x8 a0h = *(const bf16x8*)(&Hmhi[l15 * 136 + koff]);
          bf16x8 a0l = *(const bf16x8*)(&Hmlo[l15 * 136 + koff]);
          bf16x8 a1h = *(const bf16x8*)(&Hmhi[(16 + l15) * 136 + koff]);
          bf16x8 a1l = *(const bf16x8*)(&Hmlo[(16 + l15) * 136 + koff]);
          const u16* pb0 = Bw1 + (size_t)(n0*16 + l15) * 128 + koff;
          const u16* pb1 = Bw1 + (size_t)(n1*16 + l15) * 128 + koff;
          bf16x8 b0h = *(const bf16x8*)pb0, b0l = *(const bf16x8*)(pb0 + WOFF);
          bf16x8 b1h = *(const bf16x8*)pb1, b1l = *(const bf16x8*)(pb1 + WOFF);
          acc00 = mfma_(a0l,b0h, mfma_(a0h,b0l, mfma_(a0h,b0h, acc00)));
          acc10 = mfma_(a1l,b0h, mfma_(a1h,b0l, mfma_(a1h,b0h, acc10)));
          acc01 = mfma_(a0l,b1h, mfma_(a0h,b1l, mfma_(a0h,b1h, acc01)));
          acc11 = mfma_(a1l,b1h, mfma_(a1h,b1l, mfma_(a1h,b1h, acc11)));
        }
        // --- seg2 (coherent msg) ---
        {
          const u16* pa0 = Am + (size_t)l15 * 128 + koff;
          const u16* pa1 = Am + (size_t)(16 + l15) * 128 + koff;
          bf16x8 a0h = ald16(pa0), a0l = ald16(pa0 + SLICE);
          bf16x8 a1h = ald16(pa1), a1l = ald16(pa1 + SLICE);
          const u16* pb0 = Bw2 + (size_t)(n0*16 + l15) * 128 + koff;
          const u16* pb1 = Bw2 + (size_t)(n1*16 + l15) * 128 + koff;
          bf16x8 b0h = *(const bf16x8*)pb0, b0l = *(const bf16x8*)(pb0 + WOFF);
          bf16x8 b1h = *(const bf16x8*)pb1, b1l = *(const bf16x8*)(pb1 + WOFF);
          acc00 = mfma_(a0l,b0h, mfma_(a0h,b0l, mfma_(a0h,b0h, acc00)));
          acc10 = mfma_(a1l,b0h, mfma_(a1h,b0l, mfma_(a1h,b0h, acc10)));
          acc01 = mfma_(a0l,b1h, mfma_(a0h,b1l, mfma_(a0h,b1h, acc01)));
          acc11 = mfma_(a1l,b1h, mfma_(a1h,b1l, mfma_(a1h,b1h, acc11)));
        }
      }
    }
    __syncthreads();   // all waves done reading Hm before overwrite

    // epilogue: tanh (fp32) -> split bf16 into Hm (LDS only)
    {
      float bs0 = biasf[r*H_ + n0*16 + l15];
      float bs1 = biasf[r*H_ + n1*16 + l15];
      #pragma unroll
      for (int rr = 0; rr < 4; ++rr) {
        int b0r = quad*4 + rr;
        int b1r = 16 + quad*4 + rr;
        u16 h, l;
        split2(fast_tanh(acc00[rr] + bs0), h, l);
        Hmhi[b0r*136 + n0*16 + l15] = h; Hmlo[b0r*136 + n0*16 + l15] = l;
        split2(fast_tanh(acc10[rr] + bs0), h, l);
        Hmhi[b1r*136 + n0*16 + l15] = h; Hmlo[b1r*136 + n0*16 + l15] = l;
        split2(fast_tanh(acc01[rr] + bs1), h, l);
        Hmhi[b0r*136 + n1*16 + l15] = h; Hmlo[b0r*136 + n1*16 + l15] = l;
        split2(fast_tanh(acc11[rr] + bs1), h, l);
        Hmhi[b1r*136 + n1*16 + l15] = h; Hmlo[b1r*136 + n1*16 + l15] = l;
      }
    }
    __syncthreads();   // Hm ready

    // coalesced coherent H_t write (for next step's phase A)
    {
      u16* Hn = Hnext + (size_t)r * (B_*H_);
      for (int e = tid; e < 32 * 32; e += 256) {
        int row = e >> 5, c = (e & 31) * 4;
        ast8(Hn + row * H_ + c,         *(const ull*)&Hmhi[row * 136 + c]);
        ast8(Hn + SLICE + row * H_ + c, *(const ull*)&Hmlo[row * 136 + c]);
      }
    }

    // fused out-projection: part[r] = Ht[r] @ Wout[r] (fp32, coherent)
    {
      const int o = wv * 16 + l15;
      const u16* Bo = WoutT + (size_t)o * (R_*H_) + (size_t)r * H_;
      f32x4 y0 = {0,0,0,0}, y1 = {0,0,0,0};
      #pragma unroll
      for (int kk = 0; kk < 4; ++kk) {
        int koff = kk * 32 + quad * 8;
        bf16x8 a0h = *(const bf16x8*)(&Hmhi[l15 * 136 + koff]);
        bf16x8 a0l = *(const bf16x8*)(&Hmlo[l15 * 136 + koff]);
        bf16x8 a1h = *(const bf16x8*)(&Hmhi[(16 + l15) * 136 + koff]);
        bf16x8 a1l = *(const bf16x8*)(&Hmlo[(16 + l15) * 136 + koff]);
        bf16x8 b0h = *(const bf16x8*)(Bo + koff);
        bf16x8 b0l = *(const bf16x8*)(Bo + OOFF + koff);
        y0 = mfma_(a0l,b0h, mfma_(a0h,b0l, mfma_(a0h,b0h, y0)));
        y1 = mfma_(a1l,b0h, mfma_(a1h,b0l, mfma_(a1h,b0h, y1)));
      }
      float* pp = part + (size_t)r * (B_*O_);
      #pragma unroll
      for (int rr = 0; rr < 4; ++rr) {
        astf(pp + (quad*4 + rr)*O_ + o,      y0[rr]);
        astf(pp + (16 + quad*4 + rr)*O_ + o, y1[rr]);
      }
    }
    ++gen; grid_barrier(flags, gen, w, tid);
  }

  // -------- tail: reduce partials of step T-1 --------
  if (w >= 64 && w < 72) {
    int e = (w - 64) * 256 + tid;
    float s = 0.f;
    #pragma unroll 4
    for (int r2 = 0; r2 < R_; ++r2) s += aldf(part + r2 * (B_*O_) + e);
    out[(size_t)(T_-1) * (B_*O_) + e] = s + boutf[e & (O_-1)];
  }
}

extern "C" void kernel_launch(void* const* d_in, const int* in_sizes, int n_in,
                              void* d_out, int out_size, void* d_ws, size_t ws_size,
                              hipStream_t stream) {
  const void* xp    = d_in[0];
  const void* Cp    = d_in[1];
  const void* Wih   = d_in[2];
  const void* Whh   = d_in[3];
  const void* Wrhh  = d_in[4];
  const void* biasp = d_in[5];
  const void* Wout  = d_in[6];
  const void* boutp = d_in[7];
  float* outp = (float*)d_out;    // fp32 output

  char* ws = (char*)d_ws;
  size_t off = 0;
  auto carve = [&](size_t bytes) -> void* {
    void* p = ws + off;
    off += (bytes + 255) & ~(size_t)255;
    return p;
  };
  u16*   xb    = (u16*)carve((size_t)2 * XOFF * 2);            // hi|lo
  u16*   Hb    = (u16*)carve((size_t)4 * SLICE * 2);           // 2 slices x hi|lo
  u16*   msgp  = (u16*)carve((size_t)2 * SLICE * 2);           // hi|lo
  u16*   wihT  = (u16*)carve((size_t)2 * WOFF * 2);
  u16*   whhT  = (u16*)carve((size_t)2 * WOFF * 2);
  u16*   wrhhT = (u16*)carve((size_t)2 * WOFF * 2);
  u16*   woutT = (u16*)carve((size_t)2 * OOFF * 2);
  u16*   ctp   = (u16*)carve((size_t)2 * CTN * 2);
  float* biasf = (float*)carve((size_t)R_ * H_ * 4);
  float* boutf = (float*)carve((size_t)O_ * 4);
  float* partp = (float*)carve((size_t)R_ * B_ * O_ * 4);
  int*   flagp = (int*)carve((size_t)NWG * 32 * 4);
  int*   modep = (int*)carve(256);

  hipMemsetAsync(Hb, 0, (size_t)2 * SLICE * 2, stream);        // H_0 hi+lo = 0
  hipMemsetAsync(flagp, 0, (size_t)NWG * 32 * 4, stream);

  probe_dtype<<<dim3(1), dim3(256), 0, stream>>>((const u16*)xp, modep);
  conv_split<<<dim3((XOFF + 255)/256), dim3(256), 0, stream>>>(xp, xb, xb + XOFF, modep, XOFF);
  conv_vec<<<dim3((R_*H_ + 255)/256), dim3(256), 0, stream>>>(biasp, biasf, modep, R_*H_);
  conv_vec<<<dim3(1), dim3(256), 0, stream>>>(boutp, boutf, modep, O_);

  transpose_kn2<<<dim3(R_ * 16), dim3(256), 0, stream>>>(Wih,  wihT,  wihT  + WOFF, I_, H_, modep);
  transpose_kn2<<<dim3(R_ * 16), dim3(256), 0, stream>>>(Whh,  whhT,  whhT  + WOFF, H_, H_, modep);
  transpose_kn2<<<dim3(R_ * 16), dim3(256), 0, stream>>>(Wrhh, wrhhT, wrhhT + WOFF, H_, H_, modep);
  transpose_kn2<<<dim3(800),     dim3(256), 0, stream>>>(Wout, woutT, woutT + OOFF, R_ * H_, O_, modep);
  make_ct2<<<dim3(56), dim3(256), 0, stream>>>(Cp, ctp, modep);

  rnn_kernel<<<dim3(NWG), dim3(256), 0, stream>>>(
      xb, Hb, msgp, wihT, whhT, wrhhT, ctp, biasf, woutT, partp, boutf, outp, flagp);
}